// Round 9
// baseline (6314.058 us; speedup 1.0000x reference)
//
#include <hip/hip_runtime.h>
#include <math.h>

#define NWG 256
#define NTH 1024   // 16 waves/WG, 4 waves/SIMD at 1 WG/CU

// agent-coherent (L2-bypassing) scalar access — the cross-XCD exchange primitive
__device__ __forceinline__ float cload(const float* p) {
    return __hip_atomic_load(p, __ATOMIC_RELAXED, __HIP_MEMORY_SCOPE_AGENT);
}
__device__ __forceinline__ void cstore(float* p, float v) {
    __hip_atomic_store(p, v, __ATOMIC_RELAXED, __HIP_MEMORY_SCOPE_AGENT);
}

__global__ void k_zero(unsigned* p, int n) {
    int i = blockIdx.x * 256 + threadIdx.x;
    if (i < n) p[i] = 0u;
}

// transpose x [64][512][16] -> xT [512][64][16] (float4 granularity)
__global__ void k_xt(const float* __restrict__ x, float* __restrict__ xT) {
    int i = blockIdx.x * 256 + threadIdx.x;
    if (i < 131072) {
        int mt = i >> 2, q = i & 3;
        int m = mt >> 9, t = mt & 511;
        float4 v = *(const float4*)(x + (size_t)i * 4);
        *(float4*)(xT + ((size_t)t * 64 + m) * 16 + q * 4) = v;
    }
}

// One persistent cooperative kernel. WG w owns h-columns c0=2w, c0+1 of BOTH
// layers (6 gate-rows per matrix), lane = chain, 16 waves k-split by 32.
// Pipeline at slot s: h0(s) | gi1(s-1)+h1(s-1) | FC(s-2) | biophys(s-3).
// h buffers: k-major [k][chain] parity double-buffers, agent-coherent access.
// ANTI-SPILL (R8 lesson): unroll-1 chunk loops + VGPR cap 128 (R8 used 84).
__global__ __launch_bounds__(NTH, 4)
void k_fused(const float* __restrict__ xT,
             const float* __restrict__ Wih0, const float* __restrict__ Whh0,
             const float* __restrict__ bih0, const float* __restrict__ bhh0,
             const float* __restrict__ Wih1, const float* __restrict__ Whh1,
             const float* __restrict__ bih1, const float* __restrict__ bhh1,
             const float* __restrict__ fcW, const float* __restrict__ fcb,
             const float* __restrict__ h0in, const float* __restrict__ th0,
             const float* __restrict__ om0, float* __restrict__ out,
             float* __restrict__ h0buf, float* __restrict__ h1buf,
             float* __restrict__ apre_g, unsigned* __restrict__ bar)
{
    const int w = blockIdx.x, tid = threadIdx.x;
    const int v = tid >> 6, m = tid & 63;     // v in 0..15
    const int c0 = w * 2;
    const int ks = v * 32;                    // 32-k slice per wave
    __shared__ float w0s[6 * 512];   // Whh0 rows (local g = gate*2 + j)
    __shared__ float wi1s[6 * 512];  // Wih1 rows
    __shared__ float w1s[6 * 512];   // Whh1 rows
    __shared__ float wihs[6 * 16];   // Wih0 rows
    __shared__ float fcrow[512];     // this WG's fc row (WGs 8..23)
    __shared__ float pl[16 * 12 * 64];
    __shared__ float pl2[16 * 64];

    for (int i = tid; i < 6 * 128; i += NTH) {
        int g = i >> 7, q = (i & 127) * 4;
        int row = (g >> 1) * 512 + c0 + (g & 1);
        *(float4*)&w0s[g * 512 + q]  = *(const float4*)(Whh0 + (size_t)row * 512 + q);
        *(float4*)&wi1s[g * 512 + q] = *(const float4*)(Wih1 + (size_t)row * 512 + q);
        *(float4*)&w1s[g * 512 + q]  = *(const float4*)(Whh1 + (size_t)row * 512 + q);
    }
    if (tid < 24) {
        int g = tid >> 2, q = (tid & 3) * 4;
        int row = (g >> 1) * 512 + c0 + (g & 1);
        *(float4*)&wihs[g * 16 + q] = *(const float4*)(Wih0 + (size_t)row * 16 + q);
    }
    const bool isFC = (w >= 8 && w < 24);
    if (isFC && tid < 128)
        *(float4*)&fcrow[tid * 4] = *(const float4*)(fcW + (size_t)(w - 8) * 512 + tid * 4);

    float b_r0=0,b_z0=0,b_in0=0,b_hn0=0, bi1r=0,bi1z=0,bi1n=0, bh1r=0,bh1z=0,bh1n=0;
    if (v < 2) {
        int c = c0 + v;
        b_r0  = bih0[c] + bhh0[c];
        b_z0  = bih0[512 + c] + bhh0[512 + c];
        b_in0 = bih0[1024 + c]; b_hn0 = bhh0[1024 + c];
        bi1r = bih1[c]; bi1z = bih1[512 + c]; bi1n = bih1[1024 + c];
        bh1r = bhh1[c]; bh1z = bhh1[512 + c]; bh1n = bhh1[1024 + c];
    }
    // biophys state: WG 0, thread = chain*8 + joint (first 512 threads)
    float th = 0.f, om = 0.f, fb0 = 0.f, fb1 = 0.f;
    if (w == 0 && tid < 512) {
        th = th0[tid]; om = om0[tid];
        fb0 = fcb[2 * (tid & 7)]; fb1 = fcb[2 * (tid & 7) + 1];
    }
    const float* h1in = h0in + 32768;
    float gi_r = 0.f, gi_z = 0.f, gi_n = 0.f;
    __syncthreads();

    for (int s = 0; s < 515; ++s) {
        const int pw0 = s & 1, pr0 = (s + 1) & 1;
        // ---- biophys: consume apre written last slot -> theta(s-3) ----
        if (w == 0 && s >= 3 && tid < 512) {
            int mc = tid >> 3, j = tid & 7;
            const float* ap = apre_g + ((s + 1) & 1) * 1024;
            float a0 = 1.f / (1.f + expf(-(cload(&ap[(2 * j) * 64 + mc]) + fb0)));
            float a1 = 1.f / (1.f + expf(-(cload(&ap[(2 * j + 1) * 64 + mc]) + fb1)));
            float F0 = (100.f + 2000.f * a0) * (0.06f + 0.006f * a0 + 0.05f * th);
            float F1 = (100.f + 2000.f * a1) * (0.06f + 0.006f * a1 - 0.05f * th);
            float tau = 0.05f * (F1 - F0);
            float acc = (tau - 5.f * th - 0.3f * om) * 250.f;
            om += (1.f / 60.f) * acc;
            th += (1.f / 60.f) * om;
            out[((size_t)mc * 512 + (s - 3)) * 8 + j] = th;
        }
        // ---- fused phase 1+2: Whh0 & Wih1 dots over h0(s-1) ----
        if (s <= 512) {
            float a01[12];
            #pragma unroll
            for (int g = 0; g < 12; ++g) a01[g] = 0.f;
            #pragma unroll 1
            for (int kb = 0; kb < 2; ++kb) {
                float hb[16];
                if (s == 0) {
                    #pragma unroll
                    for (int q = 0; q < 4; ++q) {
                        float4 t = *(const float4*)(h0in + (size_t)m * 512 + ks + kb * 16 + q * 4);
                        hb[q*4] = t.x; hb[q*4+1] = t.y; hb[q*4+2] = t.z; hb[q*4+3] = t.w;
                    }
                } else {
                    const float* hp = h0buf + pr0 * 32768 + (ks + kb * 16) * 64 + m;
                    #pragma unroll
                    for (int i = 0; i < 16; ++i) hb[i] = cload(&hp[i * 64]);
                }
                #pragma unroll
                for (int i = 0; i < 16; ++i) {
                    float hv = hb[i];
                    int ko = ks + kb * 16 + i;
                    #pragma unroll
                    for (int g = 0; g < 6; ++g) {
                        a01[g]     += w0s[g * 512 + ko] * hv;
                        a01[6 + g] += wi1s[g * 512 + ko] * hv;
                    }
                }
            }
            #pragma unroll
            for (int g = 0; g < 12; ++g) pl[(v * 12 + g) * 64 + m] = a01[g];
        }
        __syncthreads();
        // ---- combine A: h0(s) update + gi1(s-1) registers ----
        if (v < 2) {
            int c = c0 + v;
            if (s <= 511) {
                float hr = 0.f, hz = 0.f, hn = 0.f;
                #pragma unroll
                for (int u = 0; u < 16; ++u) {
                    hr += pl[(u * 12 + v) * 64 + m];
                    hz += pl[(u * 12 + 2 + v) * 64 + m];
                    hn += pl[(u * 12 + 4 + v) * 64 + m];
                }
                const float* xp = xT + ((size_t)s * 64 + m) * 16;
                float ir = 0.f, iz = 0.f, in_ = 0.f;
                #pragma unroll
                for (int k = 0; k < 16; ++k) {
                    float xv = xp[k];
                    ir  += wihs[v * 16 + k] * xv;
                    iz  += wihs[(2 + v) * 16 + k] * xv;
                    in_ += wihs[(4 + v) * 16 + k] * xv;
                }
                float hold = (s == 0) ? h0in[(size_t)m * 512 + c]
                                      : cload(&h0buf[pr0 * 32768 + c * 64 + m]);
                float r = 1.f / (1.f + expf(-(ir + hr + b_r0)));
                float z = 1.f / (1.f + expf(-(iz + hz + b_z0)));
                float n = tanhf(in_ + b_in0 + r * (hn + b_hn0));
                cstore(&h0buf[pw0 * 32768 + c * 64 + m], (1.f - z) * n + z * hold);
            }
            if (s >= 1 && s <= 512) {
                gi_r = bi1r; gi_z = bi1z; gi_n = bi1n;
                #pragma unroll
                for (int u = 0; u < 16; ++u) {
                    gi_r += pl[(u * 12 + 6 + v) * 64 + m];
                    gi_z += pl[(u * 12 + 8 + v) * 64 + m];
                    gi_n += pl[(u * 12 + 10 + v) * 64 + m];
                }
            }
        }
        __syncthreads();
        // ---- phase 3: Whh1 dot over h1(s-2) + FC dot, streamed in 16-chunks ----
        if (s >= 1 && s <= 513) {
            float a2[6];
            #pragma unroll
            for (int g = 0; g < 6; ++g) a2[g] = 0.f;
            float fdot = 0.f;
            #pragma unroll 1
            for (int kb = 0; kb < 2; ++kb) {
                float hb[16];
                if (s == 1) {
                    #pragma unroll
                    for (int q = 0; q < 4; ++q) {
                        float4 t = *(const float4*)(h1in + (size_t)m * 512 + ks + kb * 16 + q * 4);
                        hb[q*4] = t.x; hb[q*4+1] = t.y; hb[q*4+2] = t.z; hb[q*4+3] = t.w;
                    }
                } else {
                    const float* hp = h1buf + (s & 1) * 32768 + (ks + kb * 16) * 64 + m;
                    #pragma unroll
                    for (int i = 0; i < 16; ++i) hb[i] = cload(&hp[i * 64]);
                }
                #pragma unroll
                for (int i = 0; i < 16; ++i) {
                    float hv = hb[i];
                    int ko = ks + kb * 16 + i;
                    #pragma unroll
                    for (int g = 0; g < 6; ++g) a2[g] += w1s[g * 512 + ko] * hv;
                    fdot += hv * fcrow[ko];
                }
            }
            if (s <= 512) {
                #pragma unroll
                for (int g = 0; g < 6; ++g) pl[(v * 12 + g) * 64 + m] = a2[g];
            }
            if (isFC && s >= 2) pl2[v * 64 + m] = fdot;
        }
        __syncthreads();
        // ---- combine B: h1(s-1) update ----
        if (s >= 1 && s <= 512 && v < 2) {
            int c = c0 + v;
            float hr = 0.f, hz = 0.f, hn = 0.f;
            #pragma unroll
            for (int u = 0; u < 16; ++u) {
                hr += pl[(u * 12 + v) * 64 + m];
                hz += pl[(u * 12 + 2 + v) * 64 + m];
                hn += pl[(u * 12 + 4 + v) * 64 + m];
            }
            float hold = (s == 1) ? h1in[(size_t)m * 512 + c]
                                  : cload(&h1buf[(s & 1) * 32768 + c * 64 + m]);
            float r = 1.f / (1.f + expf(-(gi_r + hr + bh1r)));
            float z = 1.f / (1.f + expf(-(gi_z + hz + bh1z)));
            float n = tanhf(gi_n + r * (hn + bh1n));
            cstore(&h1buf[((s + 1) & 1) * 32768 + c * 64 + m], (1.f - z) * n + z * hold);
        }
        if (isFC && s >= 2 && s <= 513 && v == 2) {
            float p = 0.f;
            #pragma unroll
            for (int u = 0; u < 16; ++u) p += pl2[u * 64 + m];
            cstore(&apre_g[(s & 1) * 1024 + (w - 8) * 64 + m], p);
        }
        if (s == 514) break;
        // ---- grid barrier: counter tree, no fences (data is coherent) ----
        __syncthreads();                 // compiler drains vmcnt before s_barrier
        if (tid == 0) {
            const unsigned gen = (unsigned)(s + 1);
            unsigned p = __hip_atomic_fetch_add(&bar[(w >> 4) * 16], 1u,
                                                __ATOMIC_RELAXED, __HIP_MEMORY_SCOPE_AGENT);
            if (p + 1u == 16u * gen) {
                unsigned q = __hip_atomic_fetch_add(&bar[272], 1u,
                                                    __ATOMIC_RELAXED, __HIP_MEMORY_SCOPE_AGENT);
                if (q + 1u == 16u * gen)
                    __hip_atomic_store(&bar[288], gen,
                                       __ATOMIC_RELAXED, __HIP_MEMORY_SCOPE_AGENT);
            }
            unsigned f;
            do {
                f = __hip_atomic_load(&bar[288], __ATOMIC_RELAXED,
                                      __HIP_MEMORY_SCOPE_AGENT);
                if (f < gen) __builtin_amdgcn_s_sleep(8);
            } while (f < gen);
        }
        __syncthreads();
    }
}

// ---------------------------------------------------------------------------
extern "C" void kernel_launch(void* const* d_in, const int* in_sizes, int n_in,
                              void* d_out, int out_size, void* d_ws, size_t ws_size,
                              hipStream_t stream) {
    const float* x     = (const float*)d_in[0];
    const float* W_ih0 = (const float*)d_in[1];
    const float* W_hh0 = (const float*)d_in[2];
    const float* b_ih0 = (const float*)d_in[3];
    const float* b_hh0 = (const float*)d_in[4];
    const float* W_ih1 = (const float*)d_in[5];
    const float* W_hh1 = (const float*)d_in[6];
    const float* b_ih1 = (const float*)d_in[7];
    const float* b_hh1 = (const float*)d_in[8];
    const float* fc_W  = (const float*)d_in[9];
    const float* fc_b  = (const float*)d_in[10];
    const float* h0    = (const float*)d_in[11];
    const float* th0   = (const float*)d_in[12];
    const float* om0   = (const float*)d_in[13];
    float* out = (float*)d_out;

    float* ws = (float*)d_ws;
    float* h0buf  = ws;                 // 2 x [512][64] k-major parity buffers
    float* h1buf  = h0buf + 65536;
    float* apre_g = h1buf + 65536;      // 2 x [16][64]
    unsigned* bar = (unsigned*)(apre_g + 2048);    // 512 uints
    float* xT     = (float*)(bar + 512);           // [512][64][16]

    k_zero<<<2, 256, 0, stream>>>(bar, 512);
    k_xt<<<512, 256, 0, stream>>>(x, xT);

    void* args[] = {(void*)&xT, (void*)&W_ih0, (void*)&W_hh0, (void*)&b_ih0,
                    (void*)&b_hh0, (void*)&W_ih1, (void*)&W_hh1, (void*)&b_ih1,
                    (void*)&b_hh1, (void*)&fc_W, (void*)&fc_b, (void*)&h0,
                    (void*)&th0, (void*)&om0, (void*)&out, (void*)&h0buf,
                    (void*)&h1buf, (void*)&apre_g, (void*)&bar};
    (void)hipLaunchCooperativeKernel((void*)k_fused, dim3(NWG), dim3(NTH),
                                     args, 0, stream);
}

// Round 10
// 5973.791 us; speedup vs baseline: 1.0570x; 1.0570x over previous
//
#include <hip/hip_runtime.h>
#include <math.h>

#define NWG 256
#define NTH 512

// agent-coherent (L2-bypassing) scalar access — the cross-XCD exchange primitive
__device__ __forceinline__ float cload(const float* p) {
    return __hip_atomic_load(p, __ATOMIC_RELAXED, __HIP_MEMORY_SCOPE_AGENT);
}
__device__ __forceinline__ void cstore(float* p, float v) {
    __hip_atomic_store(p, v, __ATOMIC_RELAXED, __HIP_MEMORY_SCOPE_AGENT);
}

// two-level arrive (16 groups x 16 WGs); gen is monotonic, counters never reset
__device__ __forceinline__ void bar_arrive(unsigned* tree, int w, unsigned gen) {
    unsigned p = __hip_atomic_fetch_add(&tree[(w >> 4) * 16], 1u,
                                        __ATOMIC_RELAXED, __HIP_MEMORY_SCOPE_AGENT);
    if (p + 1u == 16u * gen) {
        unsigned q = __hip_atomic_fetch_add(&tree[272], 1u,
                                            __ATOMIC_RELAXED, __HIP_MEMORY_SCOPE_AGENT);
        if (q + 1u == 16u * gen)
            __hip_atomic_store(&tree[288], gen,
                               __ATOMIC_RELAXED, __HIP_MEMORY_SCOPE_AGENT);
    }
}
__device__ __forceinline__ void bar_wait(unsigned* tree, unsigned gen) {
    unsigned f;
    do {
        f = __hip_atomic_load(&tree[288], __ATOMIC_RELAXED, __HIP_MEMORY_SCOPE_AGENT);
        if (f < gen) __builtin_amdgcn_s_sleep(2);
    } while (f < gen);
}

__global__ void k_zero(unsigned* p, int n) {
    int i = blockIdx.x * 256 + threadIdx.x;
    if (i < n) p[i] = 0u;
}

// transpose x [64][512][16] -> xT [512][64][16] (float4 granularity)
__global__ void k_xt(const float* __restrict__ x, float* __restrict__ xT) {
    int i = blockIdx.x * 256 + threadIdx.x;
    if (i < 131072) {
        int mt = i >> 2, q = i & 3;
        int m = mt >> 9, t = mt & 511;
        float4 v = *(const float4*)(x + (size_t)i * 4);
        *(float4*)(xT + ((size_t)t * 64 + m) * 16 + q * 4) = v;
    }
}

// Persistent cooperative kernel, R8 structure (512 thr, 8 waves, k-split 64)
// with SPLIT BARRIERS: h0-barrier arrives mid-step (after combine A), waited
// at next step top; h1-barrier arrives at step end, waited just before
// phase 3 — each barrier's cross-XCD latency hides behind ~half a step of
// compute. Order: [wait-h0] p1+2 | combineA [arrive-h0][wait-h1] biophys
// p3 | combineB/apre [arrive-h1].
__global__ __launch_bounds__(NTH, 2)
void k_fused(const float* __restrict__ xT,
             const float* __restrict__ Wih0, const float* __restrict__ Whh0,
             const float* __restrict__ bih0, const float* __restrict__ bhh0,
             const float* __restrict__ Wih1, const float* __restrict__ Whh1,
             const float* __restrict__ bih1, const float* __restrict__ bhh1,
             const float* __restrict__ fcW, const float* __restrict__ fcb,
             const float* __restrict__ h0in, const float* __restrict__ th0,
             const float* __restrict__ om0, float* __restrict__ out,
             float* __restrict__ h0buf, float* __restrict__ h1buf,
             float* __restrict__ apre_g, unsigned* __restrict__ bar)
{
    const int w = blockIdx.x, tid = threadIdx.x;
    const int v = tid >> 6, m = tid & 63;
    const int c0 = w * 2;
    const int ks = v * 64;
    unsigned* treeA = bar;          // h0 barrier
    unsigned* treeB = bar + 320;    // h1 barrier
    __shared__ float w0s[6 * 512];   // Whh0 rows (local g = gate*2 + j)
    __shared__ float wi1s[6 * 512];  // Wih1 rows
    __shared__ float w1s[6 * 512];   // Whh1 rows
    __shared__ float wihs[6 * 16];   // Wih0 rows
    __shared__ float fcrow[512];     // this WG's fc row (WGs 8..23)
    __shared__ float pl[8 * 12 * 64];
    __shared__ float pl2[8 * 64];

    for (int i = tid; i < 6 * 128; i += NTH) {
        int g = i >> 7, q = (i & 127) * 4;
        int row = (g >> 1) * 512 + c0 + (g & 1);
        *(float4*)&w0s[g * 512 + q]  = *(const float4*)(Whh0 + (size_t)row * 512 + q);
        *(float4*)&wi1s[g * 512 + q] = *(const float4*)(Wih1 + (size_t)row * 512 + q);
        *(float4*)&w1s[g * 512 + q]  = *(const float4*)(Whh1 + (size_t)row * 512 + q);
    }
    if (tid < 24) {
        int g = tid >> 2, q = (tid & 3) * 4;
        int row = (g >> 1) * 512 + c0 + (g & 1);
        *(float4*)&wihs[g * 16 + q] = *(const float4*)(Wih0 + (size_t)row * 16 + q);
    }
    const bool isFC = (w >= 8 && w < 24);
    if (isFC && tid < 128)
        *(float4*)&fcrow[tid * 4] = *(const float4*)(fcW + (size_t)(w - 8) * 512 + tid * 4);

    float b_r0=0,b_z0=0,b_in0=0,b_hn0=0, bi1r=0,bi1z=0,bi1n=0, bh1r=0,bh1z=0,bh1n=0;
    if (v < 2) {
        int c = c0 + v;
        b_r0  = bih0[c] + bhh0[c];
        b_z0  = bih0[512 + c] + bhh0[512 + c];
        b_in0 = bih0[1024 + c]; b_hn0 = bhh0[1024 + c];
        bi1r = bih1[c]; bi1z = bih1[512 + c]; bi1n = bih1[1024 + c];
        bh1r = bhh1[c]; bh1z = bhh1[512 + c]; bh1n = bhh1[1024 + c];
    }
    // biophys state: WG 0, thread = chain*8 + joint
    float th = 0.f, om = 0.f, fb0 = 0.f, fb1 = 0.f;
    if (w == 0) {
        th = th0[tid]; om = om0[tid];
        fb0 = fcb[2 * (tid & 7)]; fb1 = fcb[2 * (tid & 7) + 1];
    }
    const float* h1in = h0in + 32768;
    float gi_r = 0.f, gi_z = 0.f, gi_n = 0.f;
    __syncthreads();

    for (int s = 0; s < 515; ++s) {
        const int pw0 = s & 1, pr0 = (s + 1) & 1;
        // ---- wait-h0(s): h0(s-1) columns visible (arrived mid-step s-1) ----
        if (s >= 1) {
            if (tid == 0) bar_wait(treeA, (unsigned)s);
            __syncthreads();
        }
        // ---- fused phase 1+2: Whh0 & Wih1 dots over h0(s-1) ----
        if (s <= 512) {
            float a01[12];
            #pragma unroll
            for (int g = 0; g < 12; ++g) a01[g] = 0.f;
            #pragma unroll 1
            for (int kb = 0; kb < 4; ++kb) {
                float hb[16];
                if (s == 0) {
                    #pragma unroll
                    for (int q = 0; q < 4; ++q) {
                        float4 t = *(const float4*)(h0in + (size_t)m * 512 + ks + kb * 16 + q * 4);
                        hb[q*4] = t.x; hb[q*4+1] = t.y; hb[q*4+2] = t.z; hb[q*4+3] = t.w;
                    }
                } else {
                    const float* hp = h0buf + pr0 * 32768 + (ks + kb * 16) * 64 + m;
                    #pragma unroll
                    for (int i = 0; i < 16; ++i) hb[i] = cload(&hp[i * 64]);
                }
                #pragma unroll
                for (int i = 0; i < 16; ++i) {
                    float hv = hb[i];
                    int ko = ks + kb * 16 + i;
                    #pragma unroll
                    for (int g = 0; g < 6; ++g) {
                        a01[g]     += w0s[g * 512 + ko] * hv;
                        a01[6 + g] += wi1s[g * 512 + ko] * hv;
                    }
                }
            }
            #pragma unroll
            for (int g = 0; g < 12; ++g) pl[(v * 12 + g) * 64 + m] = a01[g];
        }
        __syncthreads();
        // ---- combine A: h0(s) update + gi1(s-1) registers ----
        if (v < 2) {
            int c = c0 + v;
            if (s <= 511) {
                float hr = 0.f, hz = 0.f, hn = 0.f;
                #pragma unroll
                for (int u = 0; u < 8; ++u) {
                    hr += pl[(u * 12 + v) * 64 + m];
                    hz += pl[(u * 12 + 2 + v) * 64 + m];
                    hn += pl[(u * 12 + 4 + v) * 64 + m];
                }
                const float* xp = xT + ((size_t)s * 64 + m) * 16;
                float ir = 0.f, iz = 0.f, in_ = 0.f;
                #pragma unroll
                for (int k = 0; k < 16; ++k) {
                    float xv = xp[k];
                    ir  += wihs[v * 16 + k] * xv;
                    iz  += wihs[(2 + v) * 16 + k] * xv;
                    in_ += wihs[(4 + v) * 16 + k] * xv;
                }
                float hold = (s == 0) ? h0in[(size_t)m * 512 + c]
                                      : cload(&h0buf[pr0 * 32768 + c * 64 + m]);
                float r = 1.f / (1.f + expf(-(ir + hr + b_r0)));
                float z = 1.f / (1.f + expf(-(iz + hz + b_z0)));
                float n = tanhf(in_ + b_in0 + r * (hn + b_hn0));
                cstore(&h0buf[pw0 * 32768 + c * 64 + m], (1.f - z) * n + z * hold);
            }
            if (s >= 1 && s <= 512) {
                gi_r = bi1r; gi_z = bi1z; gi_n = bi1n;
                #pragma unroll
                for (int u = 0; u < 8; ++u) {
                    gi_r += pl[(u * 12 + 6 + v) * 64 + m];
                    gi_z += pl[(u * 12 + 8 + v) * 64 + m];
                    gi_n += pl[(u * 12 + 10 + v) * 64 + m];
                }
            }
        }
        // ---- arrive-h0(s+1) + wait-h1(s): propagation hid behind p3/combineB ----
        __syncthreads();                 // drains h0 cstores (vmcnt) for all lanes
        if (tid == 0) {
            bar_arrive(treeA, w, (unsigned)(s + 1));
            bar_wait(treeB, (unsigned)s);    // s=0: trivially passed
        }
        __syncthreads();
        // ---- biophys (WG0): consume apre(s-1) -> theta(s-3); covered by wait-h1 ----
        if (w == 0 && s >= 3) {
            int mc = tid >> 3, j = tid & 7;
            const float* ap = apre_g + ((s + 1) & 1) * 1024;
            float a0 = 1.f / (1.f + expf(-(cload(&ap[(2 * j) * 64 + mc]) + fb0)));
            float a1 = 1.f / (1.f + expf(-(cload(&ap[(2 * j + 1) * 64 + mc]) + fb1)));
            float F0 = (100.f + 2000.f * a0) * (0.06f + 0.006f * a0 + 0.05f * th);
            float F1 = (100.f + 2000.f * a1) * (0.06f + 0.006f * a1 - 0.05f * th);
            float tau = 0.05f * (F1 - F0);
            float acc = (tau - 5.f * th - 0.3f * om) * 250.f;
            om += (1.f / 60.f) * acc;
            th += (1.f / 60.f) * om;
            out[((size_t)mc * 512 + (s - 3)) * 8 + j] = th;
        }
        // ---- phase 3: Whh1 dot over h1(s-1-written) + FC dot, 16-chunks ----
        if (s >= 1 && s <= 513) {
            float a2[6];
            #pragma unroll
            for (int g = 0; g < 6; ++g) a2[g] = 0.f;
            float fdot = 0.f;
            #pragma unroll 1
            for (int kb = 0; kb < 4; ++kb) {
                float hb[16];
                if (s == 1) {
                    #pragma unroll
                    for (int q = 0; q < 4; ++q) {
                        float4 t = *(const float4*)(h1in + (size_t)m * 512 + ks + kb * 16 + q * 4);
                        hb[q*4] = t.x; hb[q*4+1] = t.y; hb[q*4+2] = t.z; hb[q*4+3] = t.w;
                    }
                } else {
                    const float* hp = h1buf + (s & 1) * 32768 + (ks + kb * 16) * 64 + m;
                    #pragma unroll
                    for (int i = 0; i < 16; ++i) hb[i] = cload(&hp[i * 64]);
                }
                #pragma unroll
                for (int i = 0; i < 16; ++i) {
                    float hv = hb[i];
                    int ko = ks + kb * 16 + i;
                    #pragma unroll
                    for (int g = 0; g < 6; ++g) a2[g] += w1s[g * 512 + ko] * hv;
                    fdot += hv * fcrow[ko];
                }
            }
            if (s <= 512) {
                #pragma unroll
                for (int g = 0; g < 6; ++g) pl[(v * 12 + g) * 64 + m] = a2[g];
            }
            if (isFC && s >= 2) pl2[v * 64 + m] = fdot;
        }
        __syncthreads();
        // ---- combine B: h1(s) update + apre store ----
        if (s >= 1 && s <= 512 && v < 2) {
            int c = c0 + v;
            float hr = 0.f, hz = 0.f, hn = 0.f;
            #pragma unroll
            for (int u = 0; u < 8; ++u) {
                hr += pl[(u * 12 + v) * 64 + m];
                hz += pl[(u * 12 + 2 + v) * 64 + m];
                hn += pl[(u * 12 + 4 + v) * 64 + m];
            }
            float hold = (s == 1) ? h1in[(size_t)m * 512 + c]
                                  : cload(&h1buf[(s & 1) * 32768 + c * 64 + m]);
            float r = 1.f / (1.f + expf(-(gi_r + hr + bh1r)));
            float z = 1.f / (1.f + expf(-(gi_z + hz + bh1z)));
            float n = tanhf(gi_n + r * (hn + bh1n));
            cstore(&h1buf[((s + 1) & 1) * 32768 + c * 64 + m], (1.f - z) * n + z * hold);
        }
        if (isFC && s >= 2 && s <= 513 && v == 2) {
            float p = 0.f;
            #pragma unroll
            for (int u = 0; u < 8; ++u) p += pl2[u * 64 + m];
            cstore(&apre_g[(s & 1) * 1024 + (w - 8) * 64 + m], p);
        }
        if (s == 514) break;
        // ---- arrive-h1(s+1): end of step ----
        __syncthreads();                 // drains h1/apre cstores
        if (tid == 0) bar_arrive(treeB, w, (unsigned)(s + 1));
        // no wait here — next step top waits on treeA
    }
}

// ---------------------------------------------------------------------------
extern "C" void kernel_launch(void* const* d_in, const int* in_sizes, int n_in,
                              void* d_out, int out_size, void* d_ws, size_t ws_size,
                              hipStream_t stream) {
    const float* x     = (const float*)d_in[0];
    const float* W_ih0 = (const float*)d_in[1];
    const float* W_hh0 = (const float*)d_in[2];
    const float* b_ih0 = (const float*)d_in[3];
    const float* b_hh0 = (const float*)d_in[4];
    const float* W_ih1 = (const float*)d_in[5];
    const float* W_hh1 = (const float*)d_in[6];
    const float* b_ih1 = (const float*)d_in[7];
    const float* b_hh1 = (const float*)d_in[8];
    const float* fc_W  = (const float*)d_in[9];
    const float* fc_b  = (const float*)d_in[10];
    const float* h0    = (const float*)d_in[11];
    const float* th0   = (const float*)d_in[12];
    const float* om0   = (const float*)d_in[13];
    float* out = (float*)d_out;

    float* ws = (float*)d_ws;
    float* h0buf  = ws;                 // 2 x [512][64] k-major parity buffers
    float* h1buf  = h0buf + 65536;
    float* apre_g = h1buf + 65536;      // 2 x [16][64]
    unsigned* bar = (unsigned*)(apre_g + 2048);    // 1024 uints (two trees)
    float* xT     = (float*)(bar + 1024);          // [512][64][16]

    k_zero<<<4, 256, 0, stream>>>(bar, 1024);
    k_xt<<<512, 256, 0, stream>>>(x, xT);

    void* args[] = {(void*)&xT, (void*)&W_ih0, (void*)&W_hh0, (void*)&b_ih0,
                    (void*)&b_hh0, (void*)&W_ih1, (void*)&W_hh1, (void*)&b_ih1,
                    (void*)&b_hh1, (void*)&fc_W, (void*)&fc_b, (void*)&h0,
                    (void*)&th0, (void*)&om0, (void*)&out, (void*)&h0buf,
                    (void*)&h1buf, (void*)&apre_g, (void*)&bar};
    (void)hipLaunchCooperativeKernel((void*)k_fused, dim3(NWG), dim3(NTH),
                                     args, 0, stream);
}

// Round 11
// 5440.292 us; speedup vs baseline: 1.1606x; 1.0981x over previous
//
#include <hip/hip_runtime.h>
#include <math.h>

#define NWG 256
#define NTH 512

typedef float vf2 __attribute__((ext_vector_type(2)));

// agent-coherent (L2-bypassing) access — cross-XCD exchange primitives
__device__ __forceinline__ float cload(const float* p) {
    return __hip_atomic_load(p, __ATOMIC_RELAXED, __HIP_MEMORY_SCOPE_AGENT);
}
__device__ __forceinline__ void cstore(float* p, float v) {
    __hip_atomic_store(p, v, __ATOMIC_RELAXED, __HIP_MEMORY_SCOPE_AGENT);
}
__device__ __forceinline__ vf2 cload2(const float* p) {
    unsigned long long u = __hip_atomic_load((const unsigned long long*)p,
                                             __ATOMIC_RELAXED, __HIP_MEMORY_SCOPE_AGENT);
    vf2 r;
    r.x = __uint_as_float((unsigned)u);
    r.y = __uint_as_float((unsigned)(u >> 32));
    return r;
}
__device__ __forceinline__ void cstore2(float* p, vf2 v) {
    unsigned long long u = ((unsigned long long)__float_as_uint(v.y) << 32)
                         | (unsigned long long)__float_as_uint(v.x);
    __hip_atomic_store((unsigned long long*)p, u,
                       __ATOMIC_RELAXED, __HIP_MEMORY_SCOPE_AGENT);
}

// two-level arrive (16 groups x 16 WGs); gen monotonic, counters never reset
__device__ __forceinline__ void bar_arrive(unsigned* tree, int w, unsigned gen) {
    unsigned p = __hip_atomic_fetch_add(&tree[(w >> 4) * 16], 1u,
                                        __ATOMIC_RELAXED, __HIP_MEMORY_SCOPE_AGENT);
    if (p + 1u == 16u * gen) {
        unsigned q = __hip_atomic_fetch_add(&tree[272], 1u,
                                            __ATOMIC_RELAXED, __HIP_MEMORY_SCOPE_AGENT);
        if (q + 1u == 16u * gen)
            __hip_atomic_store(&tree[288], gen,
                               __ATOMIC_RELAXED, __HIP_MEMORY_SCOPE_AGENT);
    }
}
__device__ __forceinline__ void bar_wait(unsigned* tree, unsigned gen) {
    unsigned f;
    do {
        f = __hip_atomic_load(&tree[288], __ATOMIC_RELAXED, __HIP_MEMORY_SCOPE_AGENT);
        if (f < gen) __builtin_amdgcn_s_sleep(2);
    } while (f < gen);
}

__global__ void k_zero(unsigned* p, int n) {
    int i = blockIdx.x * 256 + threadIdx.x;
    if (i < n) p[i] = 0u;
}

// transpose x [64][512][16] -> xT [512][64][16]
__global__ void k_xt(const float* __restrict__ x, float* __restrict__ xT) {
    int i = blockIdx.x * 256 + threadIdx.x;
    if (i < 131072) {
        int mt = i >> 2, q = i & 3;
        int m = mt >> 9, t = mt & 511;
        float4 v = *(const float4*)(x + (size_t)i * 4);
        *(float4*)(xT + ((size_t)t * 64 + m) * 16 + q * 4) = v;
    }
}

// Persistent cooperative kernel (512 thr, 8 waves, k-split 64/wave).
// PACKED-PAIR layout: h buffers are [k/2][chain][2] so one 8B coherent load
// moves 2 h values; inner loops are float2 -> v_pk_fma_f32; combine phases
// run on wave v0 computing BOTH owned columns -> one paired 8B cstore.
// Split barriers as R10. Anti-spill: unroll-1 kb loops, VGPR cap 256.
__global__ __launch_bounds__(NTH, 2)
void k_fused(const float* __restrict__ xT,
             const float* __restrict__ Wih0, const float* __restrict__ Whh0,
             const float* __restrict__ bih0, const float* __restrict__ bhh0,
             const float* __restrict__ Wih1, const float* __restrict__ Whh1,
             const float* __restrict__ bih1, const float* __restrict__ bhh1,
             const float* __restrict__ fcW, const float* __restrict__ fcb,
             const float* __restrict__ h0in, const float* __restrict__ th0,
             const float* __restrict__ om0, float* __restrict__ out,
             float* __restrict__ h0buf, float* __restrict__ h1buf,
             float* __restrict__ apre_g, unsigned* __restrict__ bar)
{
    const int w = blockIdx.x, tid = threadIdx.x;
    const int v = tid >> 6, m = tid & 63;
    const int c0 = w * 2;
    const int ks = v * 64;
    unsigned* treeA = bar;          // h0 barrier
    unsigned* treeB = bar + 320;    // h1 barrier
    __shared__ float w0s[6 * 512];   // Whh0 rows (local g = gate*2 + j)
    __shared__ float wi1s[6 * 512];  // Wih1 rows
    __shared__ float w1s[6 * 512];   // Whh1 rows
    __shared__ float wihs[6 * 16];   // Wih0 rows
    __shared__ float fcrow[512];     // this WG's fc row (WGs 8..23)
    __shared__ float pl[8 * 12 * 64];
    __shared__ float pl2[8 * 64];

    for (int i = tid; i < 6 * 128; i += NTH) {
        int g = i >> 7, q = (i & 127) * 4;
        int row = (g >> 1) * 512 + c0 + (g & 1);
        *(float4*)&w0s[g * 512 + q]  = *(const float4*)(Whh0 + (size_t)row * 512 + q);
        *(float4*)&wi1s[g * 512 + q] = *(const float4*)(Wih1 + (size_t)row * 512 + q);
        *(float4*)&w1s[g * 512 + q]  = *(const float4*)(Whh1 + (size_t)row * 512 + q);
    }
    if (tid < 24) {
        int g = tid >> 2, q = (tid & 3) * 4;
        int row = (g >> 1) * 512 + c0 + (g & 1);
        *(float4*)&wihs[g * 16 + q] = *(const float4*)(Wih0 + (size_t)row * 16 + q);
    }
    const bool isFC = (w >= 8 && w < 24);
    if (isFC && tid < 128)
        *(float4*)&fcrow[tid * 4] = *(const float4*)(fcW + (size_t)(w - 8) * 512 + tid * 4);

    // v0 holds biases for BOTH columns as float2
    vf2 br0 = {0,0}, bz0 = {0,0}, bin0 = {0,0}, bhn0 = {0,0};
    vf2 bi1r = {0,0}, bi1z = {0,0}, bi1n = {0,0};
    vf2 bh1r = {0,0}, bh1z = {0,0}, bh1n = {0,0};
    if (v == 0) {
        #pragma unroll
        for (int j = 0; j < 2; ++j) {
            int c = c0 + j;
            br0[j]  = bih0[c] + bhh0[c];
            bz0[j]  = bih0[512 + c] + bhh0[512 + c];
            bin0[j] = bih0[1024 + c]; bhn0[j] = bhh0[1024 + c];
            bi1r[j] = bih1[c]; bi1z[j] = bih1[512 + c]; bi1n[j] = bih1[1024 + c];
            bh1r[j] = bhh1[c]; bh1z[j] = bhh1[512 + c]; bh1n[j] = bhh1[1024 + c];
        }
    }
    // biophys state: WG 0, thread = chain*8 + joint
    float th = 0.f, om = 0.f, fb0 = 0.f, fb1 = 0.f;
    if (w == 0) {
        th = th0[tid]; om = om0[tid];
        fb0 = fcb[2 * (tid & 7)]; fb1 = fcb[2 * (tid & 7) + 1];
    }
    const float* h1in = h0in + 32768;
    vf2 gi_r = {0,0}, gi_z = {0,0}, gi_n = {0,0};
    __syncthreads();

    for (int s = 0; s < 515; ++s) {
        const int pw0 = s & 1, pr0 = (s + 1) & 1;
        // ---- wait-h0(s): h0(s-1) pairs visible (arrived mid-step s-1) ----
        if (s >= 1) {
            if (tid == 0) bar_wait(treeA, (unsigned)s);
            __syncthreads();
        }
        // ---- fused phase 1+2: Whh0 & Wih1 dots over h0(s-1), packed pairs ----
        if (s <= 512) {
            vf2 a01[12];
            #pragma unroll
            for (int g = 0; g < 12; ++g) a01[g] = (vf2){0.f, 0.f};
            #pragma unroll 1
            for (int kb = 0; kb < 4; ++kb) {
                vf2 hb[8];
                if (s == 0) {
                    const float* hp = h0in + (size_t)m * 512 + ks + kb * 16;
                    #pragma unroll
                    for (int i = 0; i < 8; ++i) {
                        hb[i].x = hp[i * 2]; hb[i].y = hp[i * 2 + 1];
                    }
                } else {
                    const float* hp = h0buf + pr0 * 32768 + (ks / 2 + kb * 8) * 128 + m * 2;
                    #pragma unroll
                    for (int i = 0; i < 8; ++i) hb[i] = cload2(hp + i * 128);
                }
                #pragma unroll
                for (int i = 0; i < 8; ++i) {
                    vf2 hv = hb[i];
                    int ko = ks + kb * 16 + i * 2;
                    #pragma unroll
                    for (int g = 0; g < 6; ++g) {
                        a01[g]     += (*(const vf2*)&w0s[g * 512 + ko]) * hv;
                        a01[6 + g] += (*(const vf2*)&wi1s[g * 512 + ko]) * hv;
                    }
                }
            }
            #pragma unroll
            for (int g = 0; g < 12; ++g) pl[(v * 12 + g) * 64 + m] = a01[g].x + a01[g].y;
        }
        __syncthreads();
        // ---- combine A (v0, both columns): h0(s) paired update + gi1 regs ----
        if (v == 0) {
            if (s <= 511) {
                vf2 hr = {0,0}, hz = {0,0}, hn = {0,0};
                #pragma unroll
                for (int u = 0; u < 8; ++u) {
                    hr.x += pl[(u * 12 + 0) * 64 + m]; hr.y += pl[(u * 12 + 1) * 64 + m];
                    hz.x += pl[(u * 12 + 2) * 64 + m]; hz.y += pl[(u * 12 + 3) * 64 + m];
                    hn.x += pl[(u * 12 + 4) * 64 + m]; hn.y += pl[(u * 12 + 5) * 64 + m];
                }
                const float* xp = xT + ((size_t)s * 64 + m) * 16;
                vf2 ir = {0,0}, iz = {0,0}, in_ = {0,0};
                #pragma unroll
                for (int k = 0; k < 16; ++k) {
                    float xv = xp[k];
                    ir.x  += wihs[0 * 16 + k] * xv; ir.y  += wihs[1 * 16 + k] * xv;
                    iz.x  += wihs[2 * 16 + k] * xv; iz.y  += wihs[3 * 16 + k] * xv;
                    in_.x += wihs[4 * 16 + k] * xv; in_.y += wihs[5 * 16 + k] * xv;
                }
                vf2 hold;
                if (s == 0) {
                    hold.x = h0in[(size_t)m * 512 + c0];
                    hold.y = h0in[(size_t)m * 512 + c0 + 1];
                } else {
                    hold = cload2(&h0buf[pr0 * 32768 + w * 128 + m * 2]);
                }
                vf2 hnew;
                #pragma unroll
                for (int j = 0; j < 2; ++j) {
                    float r = 1.f / (1.f + expf(-(ir[j] + hr[j] + br0[j])));
                    float z = 1.f / (1.f + expf(-(iz[j] + hz[j] + bz0[j])));
                    float n = tanhf(in_[j] + bin0[j] + r * (hn[j] + bhn0[j]));
                    hnew[j] = (1.f - z) * n + z * hold[j];
                }
                cstore2(&h0buf[pw0 * 32768 + w * 128 + m * 2], hnew);
            }
            if (s >= 1 && s <= 512) {
                gi_r = bi1r; gi_z = bi1z; gi_n = bi1n;
                #pragma unroll
                for (int u = 0; u < 8; ++u) {
                    gi_r.x += pl[(u * 12 + 6) * 64 + m];  gi_r.y += pl[(u * 12 + 7) * 64 + m];
                    gi_z.x += pl[(u * 12 + 8) * 64 + m];  gi_z.y += pl[(u * 12 + 9) * 64 + m];
                    gi_n.x += pl[(u * 12 + 10) * 64 + m]; gi_n.y += pl[(u * 12 + 11) * 64 + m];
                }
            }
        }
        // ---- arrive-h0(s+1) + wait-h1(s) ----
        __syncthreads();                 // drains h0 cstores for all waves
        if (tid == 0) {
            bar_arrive(treeA, w, (unsigned)(s + 1));
            bar_wait(treeB, (unsigned)s);
        }
        __syncthreads();
        // ---- biophys (WG0): consume apre(s-1) -> theta(s-3) ----
        if (w == 0 && s >= 3) {
            int mc = tid >> 3, j = tid & 7;
            const float* ap = apre_g + ((s + 1) & 1) * 1024;
            float a0 = 1.f / (1.f + expf(-(cload(&ap[(2 * j) * 64 + mc]) + fb0)));
            float a1 = 1.f / (1.f + expf(-(cload(&ap[(2 * j + 1) * 64 + mc]) + fb1)));
            float F0 = (100.f + 2000.f * a0) * (0.06f + 0.006f * a0 + 0.05f * th);
            float F1 = (100.f + 2000.f * a1) * (0.06f + 0.006f * a1 - 0.05f * th);
            float tau = 0.05f * (F1 - F0);
            float acc = (tau - 5.f * th - 0.3f * om) * 250.f;
            om += (1.f / 60.f) * acc;
            th += (1.f / 60.f) * om;
            out[((size_t)mc * 512 + (s - 3)) * 8 + j] = th;
        }
        // ---- phase 3: Whh1 + FC dots over h1, packed pairs ----
        if (s >= 1 && s <= 513) {
            vf2 a2[6];
            #pragma unroll
            for (int g = 0; g < 6; ++g) a2[g] = (vf2){0.f, 0.f};
            vf2 fd = {0.f, 0.f};
            #pragma unroll 1
            for (int kb = 0; kb < 4; ++kb) {
                vf2 hb[8];
                if (s == 1) {
                    const float* hp = h1in + (size_t)m * 512 + ks + kb * 16;
                    #pragma unroll
                    for (int i = 0; i < 8; ++i) {
                        hb[i].x = hp[i * 2]; hb[i].y = hp[i * 2 + 1];
                    }
                } else {
                    const float* hp = h1buf + (s & 1) * 32768 + (ks / 2 + kb * 8) * 128 + m * 2;
                    #pragma unroll
                    for (int i = 0; i < 8; ++i) hb[i] = cload2(hp + i * 128);
                }
                #pragma unroll
                for (int i = 0; i < 8; ++i) {
                    vf2 hv = hb[i];
                    int ko = ks + kb * 16 + i * 2;
                    #pragma unroll
                    for (int g = 0; g < 6; ++g)
                        a2[g] += (*(const vf2*)&w1s[g * 512 + ko]) * hv;
                    fd += (*(const vf2*)&fcrow[ko]) * hv;
                }
            }
            if (s <= 512) {
                #pragma unroll
                for (int g = 0; g < 6; ++g) pl[(v * 12 + g) * 64 + m] = a2[g].x + a2[g].y;
            }
            if (isFC && s >= 2) pl2[v * 64 + m] = fd.x + fd.y;
        }
        __syncthreads();
        // ---- combine B (v0, both columns): h1(s) paired update ----
        if (s >= 1 && s <= 512 && v == 0) {
            vf2 hr = {0,0}, hz = {0,0}, hn = {0,0};
            #pragma unroll
            for (int u = 0; u < 8; ++u) {
                hr.x += pl[(u * 12 + 0) * 64 + m]; hr.y += pl[(u * 12 + 1) * 64 + m];
                hz.x += pl[(u * 12 + 2) * 64 + m]; hz.y += pl[(u * 12 + 3) * 64 + m];
                hn.x += pl[(u * 12 + 4) * 64 + m]; hn.y += pl[(u * 12 + 5) * 64 + m];
            }
            vf2 hold;
            if (s == 1) {
                hold.x = h1in[(size_t)m * 512 + c0];
                hold.y = h1in[(size_t)m * 512 + c0 + 1];
            } else {
                hold = cload2(&h1buf[(s & 1) * 32768 + w * 128 + m * 2]);
            }
            vf2 hnew;
            #pragma unroll
            for (int j = 0; j < 2; ++j) {
                float r = 1.f / (1.f + expf(-(gi_r[j] + hr[j] + bh1r[j])));
                float z = 1.f / (1.f + expf(-(gi_z[j] + hz[j] + bh1z[j])));
                float n = tanhf(gi_n[j] + r * (hn[j] + bh1n[j]));
                hnew[j] = (1.f - z) * n + z * hold[j];
            }
            cstore2(&h1buf[((s + 1) & 1) * 32768 + w * 128 + m * 2], hnew);
        }
        if (isFC && s >= 2 && s <= 513 && v == 2) {
            float p = 0.f;
            #pragma unroll
            for (int u = 0; u < 8; ++u) p += pl2[u * 64 + m];
            cstore(&apre_g[(s & 1) * 1024 + (w - 8) * 64 + m], p);
        }
        if (s == 514) break;
        // ---- arrive-h1(s+1): end of step ----
        __syncthreads();                 // drains h1/apre cstores
        if (tid == 0) bar_arrive(treeB, w, (unsigned)(s + 1));
    }
}

// ---------------------------------------------------------------------------
extern "C" void kernel_launch(void* const* d_in, const int* in_sizes, int n_in,
                              void* d_out, int out_size, void* d_ws, size_t ws_size,
                              hipStream_t stream) {
    const float* x     = (const float*)d_in[0];
    const float* W_ih0 = (const float*)d_in[1];
    const float* W_hh0 = (const float*)d_in[2];
    const float* b_ih0 = (const float*)d_in[3];
    const float* b_hh0 = (const float*)d_in[4];
    const float* W_ih1 = (const float*)d_in[5];
    const float* W_hh1 = (const float*)d_in[6];
    const float* b_ih1 = (const float*)d_in[7];
    const float* b_hh1 = (const float*)d_in[8];
    const float* fc_W  = (const float*)d_in[9];
    const float* fc_b  = (const float*)d_in[10];
    const float* h0    = (const float*)d_in[11];
    const float* th0   = (const float*)d_in[12];
    const float* om0   = (const float*)d_in[13];
    float* out = (float*)d_out;

    float* ws = (float*)d_ws;
    float* h0buf  = ws;                 // 2 x [256 pairs][64 chains][2] parity buffers
    float* h1buf  = h0buf + 65536;
    float* apre_g = h1buf + 65536;      // 2 x [16][64]
    unsigned* bar = (unsigned*)(apre_g + 2048);    // 1024 uints (two trees)
    float* xT     = (float*)(bar + 1024);          // [512][64][16]

    k_zero<<<4, 256, 0, stream>>>(bar, 1024);
    k_xt<<<512, 256, 0, stream>>>(x, xT);

    void* args[] = {(void*)&xT, (void*)&W_ih0, (void*)&W_hh0, (void*)&b_ih0,
                    (void*)&b_hh0, (void*)&W_ih1, (void*)&W_hh1, (void*)&b_ih1,
                    (void*)&b_hh1, (void*)&fc_W, (void*)&fc_b, (void*)&h0,
                    (void*)&th0, (void*)&om0, (void*)&out, (void*)&h0buf,
                    (void*)&h1buf, (void*)&apre_g, (void*)&bar};
    (void)hipLaunchCooperativeKernel((void*)k_fused, dim3(NWG), dim3(NTH),
                                     args, 0, stream);
}